// Round 5
// baseline (338.408 us; speedup 1.0000x reference)
//
#include <hip/hip_runtime.h>

typedef unsigned short u16;
typedef unsigned int   u32;
typedef unsigned long long u64;

typedef __attribute__((ext_vector_type(8))) short short8;
typedef __attribute__((ext_vector_type(4))) float f32x4;

#define DEV static __device__ __forceinline__

// POW10F[p][k] = 10^k mod p  (primes 7,11,13,17,19,23,29,31,37)
__constant__ float POW10F[9][10] = {
  {1,3,2,6,4,5,1,3,2,6},
  {1,10,1,10,1,10,1,10,1,10},
  {1,10,9,12,3,4,1,10,9,12},
  {1,10,15,14,4,6,9,5,16,7},
  {1,10,5,12,6,3,11,15,17,18},
  {1,10,8,11,18,19,6,14,2,20},
  {1,10,13,14,24,8,22,17,25,18},
  {1,10,7,8,18,25,2,20,14,16},
  {1,10,26,1,10,26,1,10,26,1},
};

#define M_TOTAL  247357937827ull
#define M_HALF   123678968913ull

DEV u16 f2bf_rne(float f){
  u32 u = __float_as_uint(f);
  return (u16)((u + 0x7FFFu + ((u >> 16) & 1u)) >> 16);
}
DEV float bf2f(u16 v){ return __uint_as_float(((u32)v) << 16); }

DEV short8 pack_bf16(float4 a, float4 b){
  union { short8 s; u32 u[4]; } r;
  r.u[0] = (__float_as_uint(a.x) >> 16) | (__float_as_uint(a.y) & 0xFFFF0000u);
  r.u[1] = (__float_as_uint(a.z) >> 16) | (__float_as_uint(a.w) & 0xFFFF0000u);
  r.u[2] = (__float_as_uint(b.x) >> 16) | (__float_as_uint(b.y) & 0xFFFF0000u);
  r.u[3] = (__float_as_uint(b.z) >> 16) | (__float_as_uint(b.w) & 0xFFFF0000u);
  return r.s;
}

DEV int modpow6(int b, int e, int p){
  int res = 1; b %= p;
  #pragma unroll
  for (int i = 0; i < 6; ++i){
    if (e & 1) res = (res * b) % p;
    b = (b * b) % p;
    e >>= 1;
  }
  return res;
}

// Wave-private phase fence: DS ops complete in order within a wave.
#define WAVE_SYNC() do { \
  asm volatile("s_waitcnt lgkmcnt(0)" ::: "memory"); \
  __builtin_amdgcn_sched_barrier(0); \
} while (0)

// ---------------- prelude: per-batch scan (blocks 0..15) + weight repack (16..76) ----------------
__global__ void prelude_kernel(const int* __restrict__ ids, const float* __restrict__ W1,
                               const float* __restrict__ W2, int* __restrict__ op_idx,
                               float* __restrict__ has_eq, u16* __restrict__ w1f,
                               u16* __restrict__ w2f){
  __shared__ int smin[256];
  __shared__ int seq[256];
  int bid = blockIdx.x, tid = threadIdx.x;
  if (bid < 16){
    int b = bid;
    int best = 2048, eq = 0;
    for (int i = tid; i < 2048; i += 256){
      int t = ids[b * 2048 + i];
      if (t >= 20 && t < 25) best = min(best, i);
      eq |= (t == 28) ? 1 : 0;
    }
    smin[tid] = best; seq[tid] = eq;
    __syncthreads();
    for (int s = 128; s > 0; s >>= 1){
      if (tid < s){ smin[tid] = min(smin[tid], smin[tid + s]); seq[tid] |= seq[tid + s]; }
      __syncthreads();
    }
    if (tid == 0){
      int op = -1;
      if (smin[0] < 2048) op = ids[b * 2048 + smin[0]] - 20;
      op_idx[b] = op;
      has_eq[b] = seq[0] ? 1.0f : 0.0f;
    }
  } else {
    int t = (bid - 16) * 256 + tid;   // 0..15615
    if (t < 12288){
      int blk = t >> 6, L = t & 63;
      int T = blk >> 3, b = blk & 7;
      int q = L >> 4, ln = L & 15;
      #pragma unroll
      for (int j = 0; j < 8; ++j){
        int k = 32 * T + 8 * q + j;
        int n = 16 * b + ln;
        w1f[(size_t)blk * 512 + L * 8 + j] = f2bf_rne(W1[k * 128 + n]);
      }
    } else {
      int t2 = t - 12288;             // 0..3327
      int blk = t2 >> 6, L = t2 & 63;
      int ts = blk / 13, b2 = blk % 13;
      int q = L >> 4, ln = L & 15;
      #pragma unroll
      for (int j = 0; j < 8; ++j){
        int k = 32 * ts + 8 * q + j;
        int n = 16 * b2 + ln;
        w2f[(size_t)blk * 512 + L * 8 + j] = (n < 200) ? f2bf_rne(W2[k * 200 + n]) : (u16)0;
      }
    }
  }
}

// ---------------- mega: 16-token blocks, 2 waves (N-split), 4096 waves total ----------------
// LDS 10880B/block: hidf [0,4096) A2-frags (reused per-wave scratch after barrier #2),
//                   logit [4096,10880): [16][212] u16.
// Barriers: exactly 2 (hid exchange, logits). All later phases token-partitioned per wave.
__launch_bounds__(128, 4)
__global__ void mega_kernel(const float* __restrict__ h, const u16* __restrict__ w1f,
                            const u16* __restrict__ w2f, const float* __restrict__ b1,
                            const float* __restrict__ b2, const float* __restrict__ Winj,
                            const float* __restrict__ binj, const float* __restrict__ gate,
                            const int* __restrict__ op_idx_ws, const float* __restrict__ has_eq_ws,
                            float* __restrict__ dout){
  __shared__ __align__(16) char lds[10880];
  u16* hidf  = (u16*)lds;                    // [2048] u16 A2-frags
  u16* logit = (u16*)(lds + 4096);           // [16][212] u16

  const int tid  = threadIdx.x;
  const int w    = tid >> 6;                 // wave 0/1
  const int lane = tid & 63;
  const int ln   = lane & 15, q = lane >> 4;
  const int wg   = blockIdx.x;
  const int tok0 = wg * 16;
  const int batch = wg >> 7;                 // 128 blocks per batch

  const int   op = op_idx_ws[batch];
  const float G  = has_eq_ws[batch] * (1.0f / (1.0f + __expf(-gate[0])));

  // wave-private scratch (overlays hidf AFTER barrier #2; a2 frags consumed before)
  char*  wls      = lds + (w << 11);         // 2KB per wave
  float* digits_s = (float*)wls;             // [8][20] f32 = 640B
  float* tab_s    = (float*)(wls + 640);     // [8][18] f32 = 576B
  u64*   ops_s    = (u64*)(wls + 1216);      // [8][5]  u64 = 320B
  float* msbv     = (float*)(wls + 1536);    // [8][12] f32 = 384B

  float b1v[4];
  #pragma unroll
  for (int b = 0; b < 4; ++b) b1v[b] = b1[w * 64 + 16 * b + ln];

  // ---- GEMM1: hid = relu(h @ W1 + b1); wave w owns N-cols [64w,64w+64), full K ----
  f32x4 acc[4];
  #pragma unroll
  for (int b = 0; b < 4; ++b) acc[b] = (f32x4)0.0f;

  const float4* ap = (const float4*)(h + (size_t)(tok0 + ln) * 768);
  float4 xa[2], xb[2];
  #pragma unroll
  for (int t = 0; t < 2; ++t){ xa[t] = ap[t * 8 + q * 2]; xb[t] = ap[t * 8 + q * 2 + 1]; }

  #pragma unroll
  for (int c = 0; c < 12; ++c){
    short8 af[2];
    #pragma unroll
    for (int t = 0; t < 2; ++t) af[t] = pack_bf16(xa[t], xb[t]);
    if (c < 11){
      const float4* ap2 = ap + (c + 1) * 16;
      #pragma unroll
      for (int t = 0; t < 2; ++t){ xa[t] = ap2[t * 8 + q * 2]; xb[t] = ap2[t * 8 + q * 2 + 1]; }
    }
    #pragma unroll
    for (int t = 0; t < 2; ++t){
      #pragma unroll
      for (int b = 0; b < 4; ++b){
        short8 bf = *(const short8*)(w1f + (size_t)((c * 2 + t) * 8 + w * 4 + b) * 512 + lane * 8);
        acc[b] = __builtin_amdgcn_mfma_f32_16x16x32_bf16(af[t], bf, acc[b], 0, 0, 0);
      }
    }
  }

  // ---- relu+bias -> hid A2-frags (wave w writes t2 = {2w, 2w+1}) ----
  // D: tok_m = q*4+r, n = 16*nb+ln; A2-frag addr: t2=nb>>1, q2=((nb&1)<<1)|(ln>>3), j=ln&7
  #pragma unroll
  for (int b = 0; b < 4; ++b){
    int nb = w * 4 + b;
    int t2 = nb >> 1;
    int q2 = ((nb & 1) << 1) | (ln >> 3);
    int j  = ln & 7;
    #pragma unroll
    for (int r = 0; r < 4; ++r){
      float v = fmaxf(acc[b][r] + b1v[b], 0.0f);
      int L2 = (q2 << 4) | (q * 4 + r);
      hidf[t2 * 512 + L2 * 8 + j] = (u16)(__float_as_uint(v) >> 16);
    }
  }
  __syncthreads();                            // barrier #1: hid exchange

  // ---- GEMM2: logits = hid @ W2 + b2; N-blocks 0..6 (wave0) / 7..12 (wave1) ----
  short8 a2[4];
  #pragma unroll
  for (int t = 0; t < 4; ++t) a2[t] = *(const short8*)(hidf + t * 512 + lane * 8);

  const int nstart = w * 7;
  const int ncnt   = 7 - w;
  float b2v[7];
  #pragma unroll
  for (int bb = 0; bb < 7; ++bb){
    int n = (nstart + bb) * 16 + ln;
    b2v[bb] = (bb < ncnt && n < 200) ? b2[n] : 0.0f;
  }
  f32x4 acc2[7];
  #pragma unroll
  for (int bb = 0; bb < 7; ++bb) acc2[bb] = (f32x4)0.0f;
  #pragma unroll
  for (int bb = 0; bb < 7; ++bb){
    if (bb < ncnt){
      #pragma unroll
      for (int t = 0; t < 4; ++t){
        short8 bf = *(const short8*)(w2f + (size_t)(t * 13 + nstart + bb) * 512 + lane * 8);
        acc2[bb] = __builtin_amdgcn_mfma_f32_16x16x32_bf16(a2[t], bf, acc2[bb], 0, 0, 0);
      }
    }
  }

  // dump logits bf16: [16 tok][212] u16
  #pragma unroll
  for (int bb = 0; bb < 7; ++bb){
    if (bb < ncnt){
      #pragma unroll
      for (int r = 0; r < 4; ++r){
        float v = acc2[bb][r] + b2v[bb];
        logit[(q * 4 + r) * 212 + (nstart + bb) * 16 + ln] = (u16)(__float_as_uint(v) >> 16);
      }
    }
  }
  __syncthreads();                            // barrier #2: logits complete (hidf now dead)

  // ---- wave w owns tokens [8w, 8w+8) for ALL remaining phases (no more barriers) ----

  // softmax + expected digit: 8 tok x 20 slots = 160 tasks
  #pragma unroll
  for (int i = 0; i < 3; ++i){
    int task = i * 64 + lane;
    if (task < 160){
      int tl = task / 20, slot = task % 20;
      int tok = w * 8 + tl;
      const u16* lp = logit + tok * 212 + slot * 10;
      float v[10];
      #pragma unroll
      for (int k = 0; k < 10; ++k) v[k] = bf2f(lp[k]);
      float mx = v[0];
      #pragma unroll
      for (int k = 1; k < 10; ++k) mx = fmaxf(mx, v[k]);
      float s = 0.0f, sd = 0.0f;
      #pragma unroll
      for (int k = 0; k < 10; ++k){
        float e = __expf(v[k] - mx);
        s += e; sd += e * (float)k;
      }
      float dig = sd / s;
      digits_s[tl * 20 + slot] = dig;
      int gt = tok0 + tok;
      int o = slot / 10, k10 = slot % 10;
      dout[(size_t)25165824 + (size_t)o * 327680 + (size_t)gt * 10 + k10] = dig;
    }
  }
  WAVE_SYNC();

  // t_p = sum_k d_k * (10^k mod p): 8 tok x 2 x 9 = 144 tasks
  #pragma unroll
  for (int i = 0; i < 3; ++i){
    int task = i * 64 + lane;
    if (task < 144){
      int tl = task / 18, rm = task % 18;
      int ab = rm / 9, pi = rm % 9;
      float t = 0.0f;
      #pragma unroll
      for (int k = 0; k < 10; ++k) t += digits_s[tl * 20 + ab * 10 + k] * POW10F[pi][k];
      tab_s[tl * 18 + ab * 9 + pi] = t;
    }
  }
  WAVE_SYNC();

  // residue arithmetic: 5 ops x 8 tok = 40 tasks
  {
    constexpr int PR[9] = {7, 11, 13, 17, 19, 23, 29, 31, 37};
    constexpr u64 CRTC[9] = {
      35336848261ull, 224870852570ull, 114165202074ull, 218257003965ull,
      78113032998ull, 53773464745ull, 68236672504ull, 223420072876ull, 220616539143ull
    };
    if (lane < 40){
      int o5 = lane >> 3, tl = lane & 7;
      u64 acc64 = 0;
      #pragma unroll
      for (int pi = 0; pi < 9; ++pi){
        const int p = PR[pi];
        float ta = tab_s[tl * 18 + pi], tb = tab_s[tl * 18 + 9 + pi];
        int r;
        if (o5 == 0){
          r = __float2int_rn(ta + tb) % p;
        } else if (o5 == 1){
          int s = __float2int_rn(ta - tb) % p;
          r = (s < 0) ? s + p : s;
        } else {
          int ra = __float2int_rn(ta) % p;
          int rb = __float2int_rn(tb) % p;
          if (o5 == 2) r = (ra * rb) % p;
          else if (o5 == 3) r = modpow6(ra, rb, p);
          else r = (rb == 0) ? 0 : (ra * modpow6(rb, p - 2, p)) % p;
        }
        acc64 += (u64)r * CRTC[pi];
      }
      u64 n = acc64 % M_TOTAL;
      int sign = 0;
      u64 un = n;
      if (o5 == 1 && n > M_HALF){ sign = 1; un = M_TOTAL - n; }
      u64 pk = 0;
      #pragma unroll
      for (int k = 0; k < 10; ++k){ pk |= (un % 10ull) << (4 * k); un /= 10ull; }
      pk |= ((u64)sign) << 40;
      ops_s[tl * 5 + o5] = pk;
    }
  }
  WAVE_SYNC();

  // select + MSB-reorder -> msbv[tl][0..11]
  if (lane < 8){
    int tl = lane;
    u64 pk = (op >= 0) ? ops_s[tl * 5 + op] : 0ull;
    int g[10]; int hi = -1;
    #pragma unroll
    for (int k = 0; k < 10; ++k){
      g[k] = (int)((pk >> (4 * k)) & 15ull);
      if (g[k] != 0) hi = k;
    }
    int ns = (hi >= 0) ? hi + 1 : 1;
    #pragma unroll
    for (int i = 0; i < 10; ++i)
      msbv[tl * 12 + i] = (i < ns) ? (float)g[ns - 1 - i] : -1.0f;
    msbv[tl * 12 + 10] = (float)((pk >> 40) & 1ull);
    msbv[tl * 12 + 11] = 0.0f;
  }
  WAVE_SYNC();

  // epilogue: h_prime = h + G * (msb @ Winj + binj); wave w streams its 8 rows
  {
    const float4* Wj4 = (const float4*)Winj;   // [11][192] float4
    const float4* bj4 = (const float4*)binj;   // [192] float4
    #pragma unroll
    for (int cc = 0; cc < 3; ++cc){
      const int f = cc * 64 + lane;            // float4 column index 0..191
      float4 wv[11];
      #pragma unroll
      for (int j = 0; j < 11; ++j) wv[j] = Wj4[j * 192 + f];
      float4 bj = bj4[f];
      const size_t base = (size_t)(tok0 + w * 8) * 768 + (size_t)f * 4;
      #pragma unroll 4
      for (int row = 0; row < 8; ++row){
        float4 m0 = *(const float4*)(msbv + row * 12);
        float4 m1 = *(const float4*)(msbv + row * 12 + 4);
        float4 m2 = *(const float4*)(msbv + row * 12 + 8);
        float4 hv = *(const float4*)(h + base + (size_t)row * 768);
        float ix = bj.x, iy = bj.y, iz = bj.z, iw = bj.w;
        ix += m0.x*wv[0].x + m0.y*wv[1].x + m0.z*wv[2].x + m0.w*wv[3].x
            + m1.x*wv[4].x + m1.y*wv[5].x + m1.z*wv[6].x + m1.w*wv[7].x
            + m2.x*wv[8].x + m2.y*wv[9].x + m2.z*wv[10].x;
        iy += m0.x*wv[0].y + m0.y*wv[1].y + m0.z*wv[2].y + m0.w*wv[3].y
            + m1.x*wv[4].y + m1.y*wv[5].y + m1.z*wv[6].y + m1.w*wv[7].y
            + m2.x*wv[8].y + m2.y*wv[9].y + m2.z*wv[10].y;
        iz += m0.x*wv[0].z + m0.y*wv[1].z + m0.z*wv[2].z + m0.w*wv[3].z
            + m1.x*wv[4].z + m1.y*wv[5].z + m1.z*wv[6].z + m1.w*wv[7].z
            + m2.x*wv[8].z + m2.y*wv[9].z + m2.z*wv[10].z;
        iw += m0.x*wv[0].w + m0.y*wv[1].w + m0.z*wv[2].w + m0.w*wv[3].w
            + m1.x*wv[4].w + m1.y*wv[5].w + m1.z*wv[6].w + m1.w*wv[7].w
            + m2.x*wv[8].w + m2.y*wv[9].w + m2.z*wv[10].w;
        float4 o;
        o.x = hv.x + G * ix; o.y = hv.y + G * iy;
        o.z = hv.z + G * iz; o.w = hv.w + G * iw;
        *(float4*)(dout + base + (size_t)row * 768) = o;
      }
    }
  }
}

// ---------------- launch ----------------
extern "C" void kernel_launch(void* const* d_in, const int* in_sizes, int n_in,
                              void* d_out, int out_size, void* d_ws, size_t ws_size,
                              hipStream_t stream){
  const float* h    = (const float*)d_in[0];
  const float* W1   = (const float*)d_in[1];
  const float* b1   = (const float*)d_in[2];
  const float* W2   = (const float*)d_in[3];
  const float* b2   = (const float*)d_in[4];
  const float* Winj = (const float*)d_in[5];
  const float* binj = (const float*)d_in[6];
  const float* gate = (const float*)d_in[7];
  const int*   ids  = (const int*)d_in[8];
  float* dout = (float*)d_out;

  char* ws = (char*)d_ws;
  int*   op_idx = (int*)(ws + 0);                 // 16 ints
  float* has_eq = (float*)(ws + 64);              // 16 floats
  u16*   w1f    = (u16*)(ws + 256);               // 196608 B
  u16*   w2f    = (u16*)(ws + 256 + 196608);      // 53248 B

  prelude_kernel<<<77, 256, 0, stream>>>(ids, W1, W2, op_idx, has_eq, w1f, w2f);
  mega_kernel<<<2048, 128, 0, stream>>>(h, w1f, w2f, b1, b2, Winj, binj, gate,
                                        op_idx, has_eq, dout);
}